// Round 1
// baseline (1313.816 us; speedup 1.0000x reference)
//
#include <hip/hip_runtime.h>

#define N_NODES   100000
#define N_EDGES   3200000
#define F_INP     128
#define HID       64
#define N_GRAPHS  512
#define N_CLASSES 2
#define NB_SCAN   ((N_NODES + 255) / 256)   // 391 scan blocks

// ---------------- degree + per-graph node counts ----------------
__global__ void deg_count_kernel(const int* __restrict__ ei, const int* __restrict__ batch,
                                 int* __restrict__ degi, int* __restrict__ counts) {
    int tid = blockIdx.x * blockDim.x + threadIdx.x;
    int stride = gridDim.x * blockDim.x;
    for (int e = tid; e < N_EDGES; e += stride)
        atomicAdd(&degi[ei[N_EDGES + e]], 1);          // col = target
    for (int i = tid; i < N_NODES; i += stride)
        atomicAdd(&counts[batch[i]], 1);
}

__global__ void dis_kernel(const int* __restrict__ degi, float* __restrict__ dis) {
    int i = blockIdx.x * blockDim.x + threadIdx.x;
    if (i < N_NODES) dis[i] = rsqrtf((float)degi[i] + 1.0f);  // +1 = self-loop
}

// ---------------- exclusive prefix scan over degi -> offs ----------------
__global__ void scan_block_kernel(const int* __restrict__ degi, int* __restrict__ offs,
                                  int* __restrict__ bsum) {
    __shared__ int s[256];
    int tid = threadIdx.x;
    int i = blockIdx.x * 256 + tid;
    int v = (i < N_NODES) ? degi[i] : 0;
    s[tid] = v;
    __syncthreads();
    for (int d = 1; d < 256; d <<= 1) {
        int t = (tid >= d) ? s[tid - d] : 0;
        __syncthreads();
        s[tid] += t;
        __syncthreads();
    }
    if (i < N_NODES) offs[i] = s[tid] - v;      // block-local exclusive
    if (tid == 255) bsum[blockIdx.x] = s[255];
}

__global__ void scan_top_kernel(const int* __restrict__ bsum, int* __restrict__ bsum2) {
    __shared__ int s[512];
    int tid = threadIdx.x;
    int v = (tid < NB_SCAN) ? bsum[tid] : 0;
    s[tid] = v;
    __syncthreads();
    for (int d = 1; d < 512; d <<= 1) {
        int t = (tid >= d) ? s[tid - d] : 0;
        __syncthreads();
        s[tid] += t;
        __syncthreads();
    }
    bsum2[tid] = s[tid] - v;                    // exclusive
}

__global__ void scan_add_kernel(int* __restrict__ offs, const int* __restrict__ bsum2,
                                int* __restrict__ cursor) {
    int tid = threadIdx.x;
    int i = blockIdx.x * 256 + tid;
    if (i < N_NODES) {
        int o = offs[i] + bsum2[blockIdx.x];
        offs[i] = o;
        cursor[i] = o;
    }
    if (blockIdx.x == 0 && tid == 0) offs[N_NODES] = N_EDGES;
}

// ---------------- CSR fill (col-grouped source lists) ----------------
__global__ void fill_adj_kernel(const int* __restrict__ ei, int* __restrict__ cursor,
                                int* __restrict__ adj) {
    int tid = blockIdx.x * blockDim.x + threadIdx.x;
    int stride = gridDim.x * blockDim.x;
    for (int e = tid; e < N_EDGES; e += stride) {
        int r = ei[e];                 // source
        int c = ei[N_EDGES + e];       // target
        int pos = atomicAdd(&cursor[c], 1);
        adj[pos] = r;
    }
}

// ---------------- mm1: p = dis * (x @ W1)   [N,128]@[128,64] ----------------
__global__ __launch_bounds__(256) void mm1_kernel(const float* __restrict__ x,
                                                  const float* __restrict__ W1,
                                                  const float* __restrict__ dis,
                                                  float* __restrict__ p) {
    const int lane = threadIdx.x & 63;
    const int wid  = threadIdx.x >> 6;
    float4 w[32];                      // column `lane` of W1 in regs (128 VGPRs)
#pragma unroll
    for (int kk = 0; kk < 32; ++kk)
        w[kk] = make_float4(W1[(4 * kk + 0) * HID + lane], W1[(4 * kk + 1) * HID + lane],
                            W1[(4 * kk + 2) * HID + lane], W1[(4 * kk + 3) * HID + lane]);
    const int gw = blockIdx.x * 4 + wid;
    const int tw = gridDim.x * 4;
    for (int base = gw * 2; base < N_NODES; base += tw * 2) {
        const int r0 = base, r1 = base + 1;   // N even -> r1 always valid
        const float4* x0 = (const float4*)(x + (size_t)r0 * F_INP);
        const float4* x1 = (const float4*)(x + (size_t)r1 * F_INP);
        float a0 = 0.f, a1 = 0.f;
#pragma unroll
        for (int kk = 0; kk < 32; ++kk) {
            float4 v0 = x0[kk];
            float4 v1 = x1[kk];
            a0 += v0.x * w[kk].x + v0.y * w[kk].y + v0.z * w[kk].z + v0.w * w[kk].w;
            a1 += v1.x * w[kk].x + v1.y * w[kk].y + v1.z * w[kk].z + v1.w * w[kk].w;
        }
        p[(size_t)r0 * HID + lane] = dis[r0] * a0;
        p[(size_t)r1 * HID + lane] = dis[r1] * a1;
    }
}

// ---------------- mm2: p = dis * (h @ W2)   [N,64]@[64,64] ----------------
__global__ __launch_bounds__(256) void mm2_kernel(const float* __restrict__ h,
                                                  const float* __restrict__ W2,
                                                  const float* __restrict__ dis,
                                                  float* __restrict__ p) {
    const int lane = threadIdx.x & 63;
    const int wid  = threadIdx.x >> 6;
    float4 w[16];
#pragma unroll
    for (int kk = 0; kk < 16; ++kk)
        w[kk] = make_float4(W2[(4 * kk + 0) * HID + lane], W2[(4 * kk + 1) * HID + lane],
                            W2[(4 * kk + 2) * HID + lane], W2[(4 * kk + 3) * HID + lane]);
    const int gw = blockIdx.x * 4 + wid;
    const int tw = gridDim.x * 4;
    for (int base = gw * 2; base < N_NODES; base += tw * 2) {
        const int r0 = base, r1 = base + 1;
        const float4* h0 = (const float4*)(h + (size_t)r0 * HID);
        const float4* h1 = (const float4*)(h + (size_t)r1 * HID);
        float a0 = 0.f, a1 = 0.f;
#pragma unroll
        for (int kk = 0; kk < 16; ++kk) {
            float4 v0 = h0[kk];
            float4 v1 = h1[kk];
            a0 += v0.x * w[kk].x + v0.y * w[kk].y + v0.z * w[kk].z + v0.w * w[kk].w;
            a1 += v1.x * w[kk].x + v1.y * w[kk].y + v1.z * w[kk].z + v1.w * w[kk].w;
        }
        p[(size_t)r0 * HID + lane] = dis[r0] * a0;
        p[(size_t)r1 * HID + lane] = dis[r1] * a1;
    }
}

// ---------------- gather1: h = relu(dis[c] * (p[c] + sum_{r->c} p[r]) + b1) ----------------
__global__ void gather1_kernel(const float* __restrict__ p, const int* __restrict__ adj,
                               const int* __restrict__ offs, const float* __restrict__ dis,
                               const float* __restrict__ b1, float* __restrict__ h) {
    const int lane = threadIdx.x & 63;
    const int gwave = (blockIdx.x * blockDim.x + threadIdx.x) >> 6;
    const int nwaves = (gridDim.x * blockDim.x) >> 6;
    const float bj = b1[lane];
    for (int c = gwave; c < N_NODES; c += nwaves) {
        float acc = p[(size_t)c * HID + lane];          // self-loop
        const int beg = offs[c], end = offs[c + 1];
        for (int e = beg; e < end; ++e) {
            int r = adj[e];
            acc += p[(size_t)r * HID + lane];
        }
        float v = dis[c] * acc + bj;
        h[(size_t)c * HID + lane] = fmaxf(v, 0.f);
    }
}

// ---------------- gather2 + fused mean-pool numerator ----------------
__global__ void gather2_kernel(const float* __restrict__ p, const int* __restrict__ adj,
                               const int* __restrict__ offs, const float* __restrict__ dis,
                               const float* __restrict__ b2, const int* __restrict__ batch,
                               float* __restrict__ sums) {
    const int lane = threadIdx.x & 63;
    const int gwave = (blockIdx.x * blockDim.x + threadIdx.x) >> 6;
    const int nwaves = (gridDim.x * blockDim.x) >> 6;
    const float bj = b2[lane];
    for (int c = gwave; c < N_NODES; c += nwaves) {
        float acc = p[(size_t)c * HID + lane];
        const int beg = offs[c], end = offs[c + 1];
        for (int e = beg; e < end; ++e) {
            int r = adj[e];
            acc += p[(size_t)r * HID + lane];
        }
        float v = fmaxf(dis[c] * acc + bj, 0.f);
        atomicAdd(&sums[(size_t)batch[c] * HID + lane], v);
    }
}

// ---------------- final FC: out[g] = (sums[g]/max(count,1)) @ Wfc + bfc ----------------
__global__ void fc_kernel(const float* __restrict__ sums, const int* __restrict__ counts,
                          const float* __restrict__ Wfc, const float* __restrict__ bfc,
                          float* __restrict__ out) {
    const int g = blockIdx.x;
    const int j = threadIdx.x;
    float cnt = fmaxf((float)counts[g], 1.0f);
    float pj = sums[(size_t)g * HID + j] / cnt;
    float a0 = pj * Wfc[j * N_CLASSES + 0];
    float a1 = pj * Wfc[j * N_CLASSES + 1];
    for (int off = 32; off > 0; off >>= 1) {
        a0 += __shfl_down(a0, off, 64);
        a1 += __shfl_down(a1, off, 64);
    }
    if (j == 0) {
        out[g * N_CLASSES + 0] = a0 + bfc[0];
        out[g * N_CLASSES + 1] = a1 + bfc[1];
    }
}

extern "C" void kernel_launch(void* const* d_in, const int* in_sizes, int n_in,
                              void* d_out, int out_size, void* d_ws, size_t ws_size,
                              hipStream_t stream) {
    const float* x     = (const float*)d_in[0];
    const int*   ei    = (const int*)d_in[1];   // [2,E]: row=ei[0:E], col=ei[E:2E]
    const int*   batch = (const int*)d_in[2];
    const float* W1    = (const float*)d_in[3];
    const float* b1    = (const float*)d_in[4];
    const float* W2    = (const float*)d_in[5];
    const float* b2    = (const float*)d_in[6];
    const float* Wfc   = (const float*)d_in[7];
    const float* bfc   = (const float*)d_in[8];
    float* out = (float*)d_out;

    char* ws = (char*)d_ws;
    size_t off = 0;
    auto alloc = [&](size_t bytes) -> void* {
        void* pp = ws + off;
        off += (bytes + 255) & ~(size_t)255;
        return pp;
    };
    int*   degi   = (int*)alloc((size_t)N_NODES * 4);
    int*   offs   = (int*)alloc((size_t)(N_NODES + 1) * 4);
    int*   cursor = (int*)alloc((size_t)N_NODES * 4);
    int*   bsum   = (int*)alloc(512 * 4);
    int*   bsum2  = (int*)alloc(512 * 4);
    float* dis    = (float*)alloc((size_t)N_NODES * 4);
    int*   adj    = (int*)alloc((size_t)N_EDGES * 4);
    float* p      = (float*)alloc((size_t)N_NODES * HID * 4);   // p1 then p2 (reused)
    float* h      = (float*)alloc((size_t)N_NODES * HID * 4);   // relu layer-1 output
    float* sums   = (float*)alloc((size_t)N_GRAPHS * HID * 4);
    int*   counts = (int*)alloc((size_t)N_GRAPHS * 4);

    hipMemsetAsync(degi, 0, (size_t)N_NODES * 4, stream);
    hipMemsetAsync(counts, 0, (size_t)N_GRAPHS * 4, stream);
    hipMemsetAsync(sums, 0, (size_t)N_GRAPHS * HID * 4, stream);

    deg_count_kernel<<<2048, 256, 0, stream>>>(ei, batch, degi, counts);
    dis_kernel<<<(N_NODES + 255) / 256, 256, 0, stream>>>(degi, dis);
    scan_block_kernel<<<NB_SCAN, 256, 0, stream>>>(degi, offs, bsum);
    scan_top_kernel<<<1, 512, 0, stream>>>(bsum, bsum2);
    scan_add_kernel<<<NB_SCAN, 256, 0, stream>>>(offs, bsum2, cursor);
    fill_adj_kernel<<<4096, 256, 0, stream>>>(ei, cursor, adj);
    mm1_kernel<<<1024, 256, 0, stream>>>(x, W1, dis, p);
    gather1_kernel<<<2048, 256, 0, stream>>>(p, adj, offs, dis, b1, h);
    mm2_kernel<<<1024, 256, 0, stream>>>(h, W2, dis, p);
    gather2_kernel<<<2048, 256, 0, stream>>>(p, adj, offs, dis, b2, batch, sums);
    fc_kernel<<<N_GRAPHS, 64, 0, stream>>>(sums, counts, Wfc, bfc, out);
}